// Round 1
// baseline (220.590 us; speedup 1.0000x reference)
//
#include <hip/hip_runtime.h>

#define DIMM 1024
#define NHEADS 16
#define HDIM 64
#define WIN 1024
#define GATEIN 20
#define BB 2
#define TT 2048
#define MTOT (BB*TT)   // 4096

typedef __attribute__((ext_vector_type(8))) short short8;
typedef __attribute__((ext_vector_type(4))) float f32x4;
typedef const __attribute__((address_space(1))) void gvoid_t;
typedef __attribute__((address_space(3))) void lvoid_t;

__device__ __forceinline__ unsigned short f2b(float f) {
  union { float f; unsigned u; } c; c.f = f;
  unsigned u = c.u + 0x7fffu + ((c.u >> 16) & 1u);
  return (unsigned short)(u >> 16);
}
__device__ __forceinline__ float b2f(unsigned short s) {
  union { unsigned u; float f; } c; c.u = ((unsigned)s) << 16;
  return c.f;
}

// ---------------- conversion f32 -> bf16 (4 elems/thread) ----------------
__global__ void cvt_bf16_kernel(const float* __restrict__ src,
                                unsigned short* __restrict__ dst, int n4) {
  int i = blockIdx.x * blockDim.x + threadIdx.x;
  if (i >= n4) return;
  float4 v = ((const float4*)src)[i];
  union { unsigned short s[4]; uint2 u; } o;
  o.s[0] = f2b(v.x); o.s[1] = f2b(v.y); o.s[2] = f2b(v.z); o.s[3] = f2b(v.w);
  *(uint2*)(dst + (size_t)i * 4) = o.u;
}

// ---------------- bias concat [bq|bk|bv] -> 3072 ----------------
__global__ void bias_cat_kernel(const float* __restrict__ bq, const float* __restrict__ bk,
                                const float* __restrict__ bv, float* __restrict__ out) {
  int i = blockIdx.x * blockDim.x + threadIdx.x;
  if (i >= 3072) return;
  out[i] = (i < 1024) ? bq[i] : (i < 2048) ? bk[i - 1024] : bv[i - 2048];
}

// ---------------- gate = sigmoid(x[:, :20] @ Wg^T + bg), [M][H] f32 ----------------
__global__ void gate_kernel(const float* __restrict__ x, const float* __restrict__ Wg,
                            const float* __restrict__ bg, float* __restrict__ gate) {
  int i = blockIdx.x * blockDim.x + threadIdx.x;   // M*H
  if (i >= MTOT * NHEADS) return;
  int h = i & 15;
  int m = i >> 4;
  const float* xr = x + (size_t)m * DIMM;
  const float* wr = Wg + h * GATEIN;
  float z = bg[h];
#pragma unroll
  for (int g = 0; g < GATEIN; ++g) z += xr[g] * wr[g];
  gate[i] = 1.f / (1.f + __expf(-z));
}

// ---------------- GEMM: C[M,N] = A[M,K] @ Bw[N,K]^T + bias, bf16 in, f32 acc ----------------
// 128x128 tile, 4 waves (2x2 of 64x64), BK=32, global_load_lds staging (m97 structure)
template<int OUTBF>
__global__ __launch_bounds__(256) void gemm_bt(const unsigned short* __restrict__ A,
                                               const unsigned short* __restrict__ Bw,
                                               const float* __restrict__ bias,
                                               void* __restrict__ Cout,
                                               int M, int N, int K) {
  __shared__ __align__(16) unsigned short As[128 * 32];
  __shared__ __align__(16) unsigned short Bs[128 * 32];
  const int tid = threadIdx.x;
  const int lane = tid & 63, wid = tid >> 6;
  const int g = lane >> 4, r16 = lane & 15;
  const int m0 = blockIdx.y * 128, n0 = blockIdx.x * 128;
  const int wr = (wid >> 1) * 64, wc = (wid & 1) * 64;
  const int wbase = wid * 64;   // wave-uniform slot base

  f32x4 acc[4][4];
#pragma unroll
  for (int i = 0; i < 4; ++i)
#pragma unroll
    for (int j = 0; j < 4; ++j) acc[i][j] = (f32x4){0.f, 0.f, 0.f, 0.f};

  for (int k0 = 0; k0 < K; k0 += 32) {
#pragma unroll
    for (int j = 0; j < 2; ++j) {
      int sbase = j * 256 + wbase;          // wave-uniform
      int s = sbase + lane;                 // per-lane slot: row = s>>2, kchunk = s&3
      const unsigned short* gA = A + (size_t)(m0 + (s >> 2)) * K + k0 + (s & 3) * 8;
      __builtin_amdgcn_global_load_lds((gvoid_t*)gA, (lvoid_t*)((char*)As + sbase * 16), 16, 0, 0);
      const unsigned short* gB = Bw + (size_t)(n0 + (s >> 2)) * K + k0 + (s & 3) * 8;
      __builtin_amdgcn_global_load_lds((gvoid_t*)gB, (lvoid_t*)((char*)Bs + sbase * 16), 16, 0, 0);
    }
    __syncthreads();
    short8 af[4], bf[4];
#pragma unroll
    for (int mf = 0; mf < 4; ++mf)
      af[mf] = *(const short8*)(As + (wr + mf * 16 + r16) * 32 + g * 8);
#pragma unroll
    for (int nf = 0; nf < 4; ++nf)
      bf[nf] = *(const short8*)(Bs + (wc + nf * 16 + r16) * 32 + g * 8);
#pragma unroll
    for (int mf = 0; mf < 4; ++mf)
#pragma unroll
      for (int nf = 0; nf < 4; ++nf)
        acc[mf][nf] = __builtin_amdgcn_mfma_f32_16x16x32_bf16(af[mf], bf[nf], acc[mf][nf], 0, 0, 0);
    __syncthreads();
  }
  // epilogue: C row = m0+wr+mf*16+g*4+rr, col = n0+wc+nf*16+r16
#pragma unroll
  for (int mf = 0; mf < 4; ++mf)
#pragma unroll
    for (int nf = 0; nf < 4; ++nf)
#pragma unroll
      for (int rr = 0; rr < 4; ++rr) {
        int m = m0 + wr + mf * 16 + g * 4 + rr;
        int n = n0 + wc + nf * 16 + r16;
        float v = acc[mf][nf][rr] + bias[n];
        if (OUTBF) ((unsigned short*)Cout)[(size_t)m * N + n] = f2b(v);
        else       ((float*)Cout)[(size_t)m * N + n] = v;
      }
}

// ---------------- RoPE + relayout: qkv_cat [M][3072] -> q_r/k_r/v_r [B*H][T][64] ----------------
__global__ void rope_kernel(const unsigned short* __restrict__ qkv,
                            const float* __restrict__ cosb, const float* __restrict__ sinb,
                            unsigned short* __restrict__ qr, unsigned short* __restrict__ kr,
                            unsigned short* __restrict__ vr) {
  int i = blockIdx.x * blockDim.x + threadIdx.x;   // M*H*32
  if (i >= MTOT * NHEADS * 32) return;
  int d = i & 31;
  int h = (i >> 5) & 15;
  int m = i >> 9;             // b*T + t
  int t = m & (TT - 1);
  int b = m >> 11;
  const unsigned short* row = qkv + (size_t)m * 3072;
  float c = cosb[t * 32 + d], s = sinb[t * 32 + d];
  float q1 = b2f(row[h * 64 + d]),        q2 = b2f(row[h * 64 + d + 32]);
  float k1 = b2f(row[1024 + h * 64 + d]), k2 = b2f(row[1024 + h * 64 + d + 32]);
  size_t o = ((size_t)(b * NHEADS + h) * TT + t) * HDIM + d;
  qr[o]      = f2b(q1 * c - q2 * s);
  qr[o + 32] = f2b(q1 * s + q2 * c);
  kr[o]      = f2b(k1 * c - k2 * s);
  kr[o + 32] = f2b(k1 * s + k2 * c);
  vr[o]      = row[2048 + h * 64 + d];
  vr[o + 32] = row[2048 + h * 64 + d + 32];
}

// ---------------- flash attention: QBLK=64 (4 waves x 16 rows), KVBLK=32, window 1024 ----------------
__global__ __launch_bounds__(256) void attn_kernel(const unsigned short* __restrict__ qr,
                                                   const unsigned short* __restrict__ kr,
                                                   const unsigned short* __restrict__ vr,
                                                   const float* __restrict__ gate,
                                                   unsigned short* __restrict__ attn_out) {
  __shared__ __align__(16) unsigned short vt[64 * 40];       // V^T tile [d][key], stride 40
  __shared__ __align__(16) unsigned short plds[4][16 * 40];  // per-wave P [qrel][key], stride 40
  const int tid = threadIdx.x;
  const int lane = tid & 63, wid = tid >> 6;
  const int g = lane >> 4, r16 = lane & 15;
  const int q0 = blockIdx.x * 64;
  const int bh = blockIdx.y;           // b*16 + h
  const int b = bh >> 4, h = bh & 15;
  const size_t base = (size_t)bh * TT * HDIM;

  // Q fragments (A-layout): row = q0 + wid*16 + r16, k = c*32 + g*8..+7
  const int qrow = q0 + wid * 16 + r16;
  short8 aq[2];
#pragma unroll
  for (int c = 0; c < 2; ++c)
    aq[c] = *(const short8*)(qr + base + (size_t)qrow * HDIM + c * 32 + g * 8);

  f32x4 acc[4];
#pragma unroll
  for (int nf = 0; nf < 4; ++nf) acc[nf] = (f32x4){0.f, 0.f, 0.f, 0.f};
  float mrun[4], lrun[4];
#pragma unroll
  for (int rr = 0; rr < 4; ++rr) { mrun[rr] = -1e30f; lrun[rr] = 0.f; }

  const int kv_lo = (q0 >= WIN) ? (q0 - WIN) : 0;
  const int kv_hi = q0 + 64;   // exclusive

  for (int kv = kv_lo; kv < kv_hi; kv += 32) {
    __syncthreads();   // previous iter's vt/plds reads complete
    {  // stage V^T cooperatively: 32 keys x 64 dims
      int key = tid >> 3;
      int d0 = (tid & 7) * 8;
      short8 vv = *(const short8*)(vr + base + (size_t)(kv + key) * HDIM + d0);
#pragma unroll
      for (int j = 0; j < 8; ++j)
        vt[(d0 + j) * 40 + key] = (unsigned short)vv[j];
    }
    __syncthreads();   // vt ready (also: prior stage drained)

    // S = Q @ K^T, two 16-key chunks
    f32x4 sacc[2];
    sacc[0] = (f32x4){0.f, 0.f, 0.f, 0.f};
    sacc[1] = (f32x4){0.f, 0.f, 0.f, 0.f};
#pragma unroll
    for (int n = 0; n < 2; ++n)
#pragma unroll
      for (int kk = 0; kk < 2; ++kk) {
        short8 bk = *(const short8*)(kr + base + (size_t)(kv + n * 16 + r16) * HDIM + kk * 32 + g * 8);
        sacc[n] = __builtin_amdgcn_mfma_f32_16x16x32_bf16(aq[kk], bk, sacc[n], 0, 0, 0);
      }

    // mask + scale, row-max over 32 keys
    float sv[2][4], lm[4];
    bool vld[2][4];
#pragma unroll
    for (int rr = 0; rr < 4; ++rr) {
      int q = q0 + wid * 16 + g * 4 + rr;
      lm[rr] = -1e30f;
#pragma unroll
      for (int n = 0; n < 2; ++n) {
        int j = kv + n * 16 + r16;
        bool valid = (j <= q) && (j + WIN >= q);
        vld[n][rr] = valid;
        float s = valid ? sacc[n][rr] * 0.125f : -1e30f;
        sv[n][rr] = s;
        lm[rr] = fmaxf(lm[rr], s);
      }
    }
#pragma unroll
    for (int off = 1; off < 16; off <<= 1)
#pragma unroll
      for (int rr = 0; rr < 4; ++rr)
        lm[rr] = fmaxf(lm[rr], __shfl_xor(lm[rr], off, 16));

    float scf[4];
#pragma unroll
    for (int rr = 0; rr < 4; ++rr) {
      float mnew = fmaxf(mrun[rr], lm[rr]);
      scf[rr] = __expf(mrun[rr] - mnew);
      mrun[rr] = mnew;
    }
    // p values, write P to LDS, rowsum
    float rs[4];
#pragma unroll
    for (int rr = 0; rr < 4; ++rr) {
      float p0 = vld[0][rr] ? __expf(sv[0][rr] - mrun[rr]) : 0.f;
      float p1 = vld[1][rr] ? __expf(sv[1][rr] - mrun[rr]) : 0.f;
      plds[wid][(g * 4 + rr) * 40 + r16]      = f2b(p0);
      plds[wid][(g * 4 + rr) * 40 + 16 + r16] = f2b(p1);
      rs[rr] = p0 + p1;
    }
#pragma unroll
    for (int off = 1; off < 16; off <<= 1)
#pragma unroll
      for (int rr = 0; rr < 4; ++rr)
        rs[rr] += __shfl_xor(rs[rr], off, 16);
#pragma unroll
    for (int rr = 0; rr < 4; ++rr) {
      lrun[rr] = lrun[rr] * scf[rr] + rs[rr];
#pragma unroll
      for (int nf = 0; nf < 4; ++nf) acc[nf][rr] *= scf[rr];
    }
    __syncthreads();   // P visible (same-wave LDS ordering included)

    // O += P @ V  (A = P from LDS, B = V^T from vt)
    short8 pa = *(const short8*)(&plds[wid][r16 * 40 + g * 8]);
#pragma unroll
    for (int nf = 0; nf < 4; ++nf) {
      short8 vb = *(const short8*)(&vt[(nf * 16 + r16) * 40 + g * 8]);
      acc[nf] = __builtin_amdgcn_mfma_f32_16x16x32_bf16(pa, vb, acc[nf], 0, 0, 0);
    }
  }

  // epilogue: normalize, gate, store bf16 to attn_out [M][1024]
#pragma unroll
  for (int rr = 0; rr < 4; ++rr) {
    int q = q0 + wid * 16 + g * 4 + rr;
    float gv = gate[((size_t)b * TT + q) * NHEADS + h];
    float inv = gv / lrun[rr];
#pragma unroll
    for (int nf = 0; nf < 4; ++nf) {
      float v = acc[nf][rr] * inv;
      attn_out[((size_t)b * TT + q) * DIMM + h * HDIM + nf * 16 + r16] = f2b(v);
    }
  }
}

// ---------------- workspace layout (bytes) ----------------
#define OFF_XB    ((size_t)0)          //  8,388,608  x bf16 [4096][1024]
#define OFF_WQKV  ((size_t)8388608)    //  6,291,456  [Wq|Wk|Wv] bf16 [3072][1024]
#define OFF_WO    ((size_t)14680064)   //  2,097,152  Wo bf16 [1024][1024]
#define OFF_BCAT  ((size_t)16777216)   //     12,288  bias concat f32 [3072]
#define OFF_QKV   ((size_t)16793600)   // 25,165,824  qkv_cat bf16 [4096][3072]
#define OFF_QR    ((size_t)41959424)   //  8,388,608  q roped [B*H][T][64]
#define OFF_KR    ((size_t)50348032)   //  8,388,608
#define OFF_VR    ((size_t)58736640)   //  8,388,608
#define OFF_ATTN  ((size_t)67125248)   //  8,388,608  gated attn out bf16 [4096][1024]
#define OFF_GATE  ((size_t)75513856)   //    262,144  gate f32 [4096][16]

extern "C" void kernel_launch(void* const* d_in, const int* in_sizes, int n_in,
                              void* d_out, int out_size, void* d_ws, size_t ws_size,
                              hipStream_t stream) {
  const float* x    = (const float*)d_in[0];
  const float* Wq   = (const float*)d_in[1];
  const float* bq   = (const float*)d_in[2];
  const float* Wk   = (const float*)d_in[3];
  const float* bk   = (const float*)d_in[4];
  const float* Wv   = (const float*)d_in[5];
  const float* bv   = (const float*)d_in[6];
  const float* Wo   = (const float*)d_in[7];
  const float* bo   = (const float*)d_in[8];
  const float* Wg   = (const float*)d_in[9];
  const float* bg   = (const float*)d_in[10];
  const float* cosb = (const float*)d_in[11];
  const float* sinb = (const float*)d_in[12];
  float* out = (float*)d_out;
  char* ws = (char*)d_ws;

  unsigned short* xb    = (unsigned short*)(ws + OFF_XB);
  unsigned short* wqkv  = (unsigned short*)(ws + OFF_WQKV);
  unsigned short* wob   = (unsigned short*)(ws + OFF_WO);
  float*          bcat  = (float*)(ws + OFF_BCAT);
  unsigned short* qkv   = (unsigned short*)(ws + OFF_QKV);
  unsigned short* q_r   = (unsigned short*)(ws + OFF_QR);
  unsigned short* k_r   = (unsigned short*)(ws + OFF_KR);
  unsigned short* v_r   = (unsigned short*)(ws + OFF_VR);
  unsigned short* attn  = (unsigned short*)(ws + OFF_ATTN);
  float*          gateb = (float*)(ws + OFF_GATE);

  // conversions
  cvt_bf16_kernel<<<4096, 256, 0, stream>>>(x, xb, 4194304 / 4);
  cvt_bf16_kernel<<<1024, 256, 0, stream>>>(Wq, wqkv,            1048576 / 4);
  cvt_bf16_kernel<<<1024, 256, 0, stream>>>(Wk, wqkv + 1048576,  1048576 / 4);
  cvt_bf16_kernel<<<1024, 256, 0, stream>>>(Wv, wqkv + 2097152,  1048576 / 4);
  cvt_bf16_kernel<<<1024, 256, 0, stream>>>(Wo, wob,             1048576 / 4);
  bias_cat_kernel<<<12, 256, 0, stream>>>(bq, bk, bv, bcat);
  gate_kernel<<<256, 256, 0, stream>>>(x, Wg, bg, gateb);

  // fused QKV projection: [4096,1024] @ [3072,1024]^T
  gemm_bt<1><<<dim3(24, 32), 256, 0, stream>>>(xb, wqkv, bcat, qkv, MTOT, 3072, 1024);

  // RoPE + relayout
  rope_kernel<<<8192, 256, 0, stream>>>(qkv, cosb, sinb, q_r, k_r, v_r);

  // windowed causal flash attention + gate
  attn_kernel<<<dim3(32, 32), 256, 0, stream>>>(q_r, k_r, v_r, gateb, attn);

  // output projection: [4096,1024] @ [1024,1024]^T + bo -> f32 out
  gemm_bt<0><<<dim3(8, 32), 256, 0, stream>>>(attn, wob, bo, out, MTOT, 1024, 1024);
}

// Round 2
// 218.656 us; speedup vs baseline: 1.0088x; 1.0088x over previous
//
#include <hip/hip_runtime.h>

#define DIMM 1024
#define NHEADS 16
#define HDIM 64
#define WIN 1024
#define GATEIN 20
#define BB 2
#define TT 2048
#define MTOT (BB*TT)   // 4096

typedef __attribute__((ext_vector_type(8))) short short8;
typedef __attribute__((ext_vector_type(4))) float f32x4;
typedef const __attribute__((address_space(1))) void gvoid_t;
typedef __attribute__((address_space(3))) void lvoid_t;

__device__ __forceinline__ unsigned short f2b(float f) {
  union { float f; unsigned u; } c; c.f = f;
  unsigned u = c.u + 0x7fffu + ((c.u >> 16) & 1u);
  return (unsigned short)(u >> 16);
}
__device__ __forceinline__ float b2f(unsigned short s) {
  union { unsigned u; float f; } c; c.u = ((unsigned)s) << 16;
  return c.f;
}

// ---------------- conversion f32 -> bf16 (4 elems/thread) ----------------
__global__ void cvt_bf16_kernel(const float* __restrict__ src,
                                unsigned short* __restrict__ dst, int n4) {
  int i = blockIdx.x * blockDim.x + threadIdx.x;
  if (i >= n4) return;
  float4 v = ((const float4*)src)[i];
  union { unsigned short s[4]; uint2 u; } o;
  o.s[0] = f2b(v.x); o.s[1] = f2b(v.y); o.s[2] = f2b(v.z); o.s[3] = f2b(v.w);
  *(uint2*)(dst + (size_t)i * 4) = o.u;
}

// ---------------- bias concat [bq|bk|bv] -> 3072 ----------------
__global__ void bias_cat_kernel(const float* __restrict__ bq, const float* __restrict__ bk,
                                const float* __restrict__ bv, float* __restrict__ out) {
  int i = blockIdx.x * blockDim.x + threadIdx.x;
  if (i >= 3072) return;
  out[i] = (i < 1024) ? bq[i] : (i < 2048) ? bk[i - 1024] : bv[i - 2048];
}

// ---------------- gate = sigmoid(x[:, :20] @ Wg^T + bg), [M][H] f32 ----------------
__global__ void gate_kernel(const float* __restrict__ x, const float* __restrict__ Wg,
                            const float* __restrict__ bg, float* __restrict__ gate) {
  int i = blockIdx.x * blockDim.x + threadIdx.x;   // M*H
  if (i >= MTOT * NHEADS) return;
  int h = i & 15;
  int m = i >> 4;
  const float* xr = x + (size_t)m * DIMM;
  const float* wr = Wg + h * GATEIN;
  float z = bg[h];
#pragma unroll
  for (int g = 0; g < GATEIN; ++g) z += xr[g] * wr[g];
  gate[i] = 1.f / (1.f + __expf(-z));
}

// ---------------- GEMM: C[M,N] = A[M,K] @ Bw[N,K]^T + bias, bf16 in, f32 acc ----------------
template<int OUTBF>
__global__ __launch_bounds__(256) void gemm_bt(const unsigned short* __restrict__ A,
                                               const unsigned short* __restrict__ Bw,
                                               const float* __restrict__ bias,
                                               void* __restrict__ Cout,
                                               int M, int N, int K) {
  __shared__ __align__(16) unsigned short As[128 * 32];
  __shared__ __align__(16) unsigned short Bs[128 * 32];
  const int tid = threadIdx.x;
  const int lane = tid & 63, wid = tid >> 6;
  const int g = lane >> 4, r16 = lane & 15;
  const int m0 = blockIdx.y * 128, n0 = blockIdx.x * 128;
  const int wr = (wid >> 1) * 64, wc = (wid & 1) * 64;
  const int wbase = wid * 64;

  f32x4 acc[4][4];
#pragma unroll
  for (int i = 0; i < 4; ++i)
#pragma unroll
    for (int j = 0; j < 4; ++j) acc[i][j] = (f32x4){0.f, 0.f, 0.f, 0.f};

  for (int k0 = 0; k0 < K; k0 += 32) {
#pragma unroll
    for (int j = 0; j < 2; ++j) {
      int sbase = j * 256 + wbase;
      int s = sbase + lane;
      const unsigned short* gA = A + (size_t)(m0 + (s >> 2)) * K + k0 + (s & 3) * 8;
      __builtin_amdgcn_global_load_lds((gvoid_t*)gA, (lvoid_t*)((char*)As + sbase * 16), 16, 0, 0);
      const unsigned short* gB = Bw + (size_t)(n0 + (s >> 2)) * K + k0 + (s & 3) * 8;
      __builtin_amdgcn_global_load_lds((gvoid_t*)gB, (lvoid_t*)((char*)Bs + sbase * 16), 16, 0, 0);
    }
    __syncthreads();
    short8 af[4], bf[4];
#pragma unroll
    for (int mf = 0; mf < 4; ++mf)
      af[mf] = *(const short8*)(As + (wr + mf * 16 + r16) * 32 + g * 8);
#pragma unroll
    for (int nf = 0; nf < 4; ++nf)
      bf[nf] = *(const short8*)(Bs + (wc + nf * 16 + r16) * 32 + g * 8);
#pragma unroll
    for (int mf = 0; mf < 4; ++mf)
#pragma unroll
      for (int nf = 0; nf < 4; ++nf)
        acc[mf][nf] = __builtin_amdgcn_mfma_f32_16x16x32_bf16(af[mf], bf[nf], acc[mf][nf], 0, 0, 0);
    __syncthreads();
  }
#pragma unroll
  for (int mf = 0; mf < 4; ++mf)
#pragma unroll
    for (int nf = 0; nf < 4; ++nf)
#pragma unroll
      for (int rr = 0; rr < 4; ++rr) {
        int m = m0 + wr + mf * 16 + g * 4 + rr;
        int n = n0 + wc + nf * 16 + r16;
        float v = acc[mf][nf][rr] + bias[n];
        if (OUTBF) ((unsigned short*)Cout)[(size_t)m * N + n] = f2b(v);
        else       ((float*)Cout)[(size_t)m * N + n] = v;
      }
}

// ---------------- RoPE + relayout: qkv_cat [M][3072] -> q_r/k_r [B*H][T][64] ----------------
__global__ void rope_kernel(const unsigned short* __restrict__ qkv,
                            const float* __restrict__ cosb, const float* __restrict__ sinb,
                            unsigned short* __restrict__ qr, unsigned short* __restrict__ kr) {
  int i = blockIdx.x * blockDim.x + threadIdx.x;   // M*H*32
  if (i >= MTOT * NHEADS * 32) return;
  int d = i & 31;
  int h = (i >> 5) & 15;
  int m = i >> 9;             // b*T + t
  int t = m & (TT - 1);
  int b = m >> 11;
  const unsigned short* row = qkv + (size_t)m * 3072;
  float c = cosb[t * 32 + d], s = sinb[t * 32 + d];
  float q1 = b2f(row[h * 64 + d]),        q2 = b2f(row[h * 64 + d + 32]);
  float k1 = b2f(row[1024 + h * 64 + d]), k2 = b2f(row[1024 + h * 64 + d + 32]);
  size_t o = ((size_t)(b * NHEADS + h) * TT + t) * HDIM + d;
  qr[o]      = f2b(q1 * c - q2 * s);
  qr[o + 32] = f2b(q1 * s + q2 * c);
  kr[o]      = f2b(k1 * c - k2 * s);
  kr[o + 32] = f2b(k1 * s + k2 * c);
}

// ---------------- V transpose: qkv[:,2048:3072] -> vt [B*H][64 d][2048 t] ----------------
__global__ __launch_bounds__(256) void vtrans_kernel(const unsigned short* __restrict__ qkv,
                                                     unsigned short* __restrict__ vt) {
  __shared__ unsigned short tile[64][66];
  const int t0 = blockIdx.x * 64;
  const int bh = blockIdx.y;
  const int b = bh >> 4, h = bh & 15;
  const int tid = threadIdx.x;
  const int r = tid >> 2;           // 0..63
  const int c0 = (tid & 3) * 16;    // 0,16,32,48
  {
    const unsigned short* src = qkv + (size_t)(b * TT + t0 + r) * 3072 + 2048 + h * 64 + c0;
    short8 v0 = *(const short8*)src;
    short8 v1 = *(const short8*)(src + 8);
#pragma unroll
    for (int j = 0; j < 8; ++j) {
      tile[r][c0 + j] = (unsigned short)v0[j];
      tile[r][c0 + 8 + j] = (unsigned short)v1[j];
    }
  }
  __syncthreads();
  {
    const int d = tid >> 2;
    const int tc = (tid & 3) * 16;
    short8 o0, o1;
#pragma unroll
    for (int j = 0; j < 8; ++j) {
      o0[j] = (short)tile[tc + j][d];
      o1[j] = (short)tile[tc + 8 + j][d];
    }
    unsigned short* dst = vt + ((size_t)bh * HDIM + d) * TT + t0 + tc;
    *(short8*)dst = o0;
    *(short8*)(dst + 8) = o1;
  }
}

// ---------------- flash attention: barrier-free, per-wave 16 q-rows, KVBLK=32 ----------------
__global__ __launch_bounds__(256) void attn_kernel(const unsigned short* __restrict__ qr,
                                                   const unsigned short* __restrict__ kr,
                                                   const unsigned short* __restrict__ vt,
                                                   const float* __restrict__ gate,
                                                   unsigned short* __restrict__ attn_out) {
  __shared__ __align__(16) unsigned short plds[4][16 * 40];  // per-wave P [qrel][key], stride 40
  const int tid = threadIdx.x;
  const int lane = tid & 63, wid = tid >> 6;
  const int g = lane >> 4, r16 = lane & 15;

  // XCD-aware swizzle: 1024 blocks, 8 XCDs -> each XCD owns 4 bh values (K/V 2MB < 4MB L2)
  const int fid = blockIdx.x;
  const int xcd = fid & 7;
  const int idx = fid >> 3;            // 0..127
  const int bh = xcd * 4 + (idx >> 5); // 4 bh per xcd
  const int qt = idx & 31;             // 32 q-tiles of 64 rows
  const int b = bh >> 4, h = bh & 15;

  const size_t kbase = (size_t)bh * TT * HDIM;   // qr/kr base
  const size_t vbase = (size_t)bh * HDIM * TT;   // vt base
  const int q0w = qt * 64 + wid * 16;            // this wave's first q row

  // Q fragments: row = q0w + r16, k(d) = kk*32 + g*8..+7
  short8 aq[2];
#pragma unroll
  for (int kk = 0; kk < 2; ++kk)
    aq[kk] = *(const short8*)(qr + kbase + (size_t)(q0w + r16) * HDIM + kk * 32 + g * 8);

  f32x4 acc[4];
#pragma unroll
  for (int nf = 0; nf < 4; ++nf) acc[nf] = (f32x4){0.f, 0.f, 0.f, 0.f};
  float mrun[4], lrun[4];
#pragma unroll
  for (int rr = 0; rr < 4; ++rr) { mrun[rr] = -1e30f; lrun[rr] = 0.f; }

  int kv_lo = q0w - WIN;
  if (kv_lo < 0) kv_lo = 0;
  kv_lo &= ~31;
  const int kv_hi = q0w + 16;   // exclusive

  for (int kv = kv_lo; kv < kv_hi; kv += 32) {
    // S = Q @ K^T (two 16-key chunks), K fragments straight from global (L2-resident)
    f32x4 sacc[2];
    sacc[0] = (f32x4){0.f, 0.f, 0.f, 0.f};
    sacc[1] = (f32x4){0.f, 0.f, 0.f, 0.f};
#pragma unroll
    for (int n = 0; n < 2; ++n)
#pragma unroll
      for (int kk = 0; kk < 2; ++kk) {
        short8 bk = *(const short8*)(kr + kbase + (size_t)(kv + n * 16 + r16) * HDIM + kk * 32 + g * 8);
        sacc[n] = __builtin_amdgcn_mfma_f32_16x16x32_bf16(aq[kk], bk, sacc[n], 0, 0, 0);
      }

    // mask + scale + row-max over 32 keys (row = q0w + g*4 + rr, owned by 16-lane group g)
    float sv[2][4], lm[4];
    bool vld[2][4];
#pragma unroll
    for (int rr = 0; rr < 4; ++rr) {
      int q = q0w + g * 4 + rr;
      lm[rr] = -1e30f;
#pragma unroll
      for (int n = 0; n < 2; ++n) {
        int j = kv + n * 16 + r16;
        bool valid = (j <= q) && (j + WIN >= q);
        vld[n][rr] = valid;
        float s = valid ? sacc[n][rr] * 0.125f : -1e30f;
        sv[n][rr] = s;
        lm[rr] = fmaxf(lm[rr], s);
      }
    }
#pragma unroll
    for (int off = 1; off < 16; off <<= 1)
#pragma unroll
      for (int rr = 0; rr < 4; ++rr)
        lm[rr] = fmaxf(lm[rr], __shfl_xor(lm[rr], off, 16));

    float scf[4];
#pragma unroll
    for (int rr = 0; rr < 4; ++rr) {
      float mnew = fmaxf(mrun[rr], lm[rr]);
      scf[rr] = __expf(mrun[rr] - mnew);
      mrun[rr] = mnew;
    }
    float rs[4];
#pragma unroll
    for (int rr = 0; rr < 4; ++rr) {
      float p0 = vld[0][rr] ? __expf(sv[0][rr] - mrun[rr]) : 0.f;
      float p1 = vld[1][rr] ? __expf(sv[1][rr] - mrun[rr]) : 0.f;
      plds[wid][(g * 4 + rr) * 40 + r16]      = f2b(p0);
      plds[wid][(g * 4 + rr) * 40 + 16 + r16] = f2b(p1);
      rs[rr] = p0 + p1;
    }
#pragma unroll
    for (int off = 1; off < 16; off <<= 1)
#pragma unroll
      for (int rr = 0; rr < 4; ++rr)
        rs[rr] += __shfl_xor(rs[rr], off, 16);
#pragma unroll
    for (int rr = 0; rr < 4; ++rr) {
      lrun[rr] = lrun[rr] * scf[rr] + rs[rr];
#pragma unroll
      for (int nf = 0; nf < 4; ++nf) acc[nf][rr] *= scf[rr];
    }

    // O += P @ V : A-frag = P[q=r16][key=g*8+j] (wave-local LDS), B-frag = V^T from global
    short8 pa = *(const short8*)(&plds[wid][r16 * 40 + g * 8]);
#pragma unroll
    for (int nf = 0; nf < 4; ++nf) {
      short8 vb = *(const short8*)(vt + vbase + (size_t)(nf * 16 + r16) * TT + kv + g * 8);
      acc[nf] = __builtin_amdgcn_mfma_f32_16x16x32_bf16(pa, vb, acc[nf], 0, 0, 0);
    }
  }

  // epilogue: normalize, gate, store bf16
#pragma unroll
  for (int rr = 0; rr < 4; ++rr) {
    int q = q0w + g * 4 + rr;
    float gv = gate[((size_t)b * TT + q) * NHEADS + h];
    float inv = gv / lrun[rr];
#pragma unroll
    for (int nf = 0; nf < 4; ++nf) {
      float v = acc[nf][rr] * inv;
      attn_out[((size_t)b * TT + q) * DIMM + h * HDIM + nf * 16 + r16] = f2b(v);
    }
  }
}

// ---------------- workspace layout (bytes) ----------------
#define OFF_XB    ((size_t)0)
#define OFF_WQKV  ((size_t)8388608)
#define OFF_WO    ((size_t)14680064)
#define OFF_BCAT  ((size_t)16777216)
#define OFF_QKV   ((size_t)16793600)
#define OFF_QR    ((size_t)41959424)
#define OFF_KR    ((size_t)50348032)
#define OFF_VT    ((size_t)58736640)
#define OFF_ATTN  ((size_t)67125248)
#define OFF_GATE  ((size_t)75513856)

extern "C" void kernel_launch(void* const* d_in, const int* in_sizes, int n_in,
                              void* d_out, int out_size, void* d_ws, size_t ws_size,
                              hipStream_t stream) {
  const float* x    = (const float*)d_in[0];
  const float* Wq   = (const float*)d_in[1];
  const float* bq   = (const float*)d_in[2];
  const float* Wk   = (const float*)d_in[3];
  const float* bk   = (const float*)d_in[4];
  const float* Wv   = (const float*)d_in[5];
  const float* bv   = (const float*)d_in[6];
  const float* Wo   = (const float*)d_in[7];
  const float* bo   = (const float*)d_in[8];
  const float* Wg   = (const float*)d_in[9];
  const float* bg   = (const float*)d_in[10];
  const float* cosb = (const float*)d_in[11];
  const float* sinb = (const float*)d_in[12];
  float* out = (float*)d_out;
  char* ws = (char*)d_ws;

  unsigned short* xb    = (unsigned short*)(ws + OFF_XB);
  unsigned short* wqkv  = (unsigned short*)(ws + OFF_WQKV);
  unsigned short* wob   = (unsigned short*)(ws + OFF_WO);
  float*          bcat  = (float*)(ws + OFF_BCAT);
  unsigned short* qkv   = (unsigned short*)(ws + OFF_QKV);
  unsigned short* q_r   = (unsigned short*)(ws + OFF_QR);
  unsigned short* k_r   = (unsigned short*)(ws + OFF_KR);
  unsigned short* v_t   = (unsigned short*)(ws + OFF_VT);
  unsigned short* attn  = (unsigned short*)(ws + OFF_ATTN);
  float*          gateb = (float*)(ws + OFF_GATE);

  cvt_bf16_kernel<<<4096, 256, 0, stream>>>(x, xb, 4194304 / 4);
  cvt_bf16_kernel<<<1024, 256, 0, stream>>>(Wq, wqkv,            1048576 / 4);
  cvt_bf16_kernel<<<1024, 256, 0, stream>>>(Wk, wqkv + 1048576,  1048576 / 4);
  cvt_bf16_kernel<<<1024, 256, 0, stream>>>(Wv, wqkv + 2097152,  1048576 / 4);
  cvt_bf16_kernel<<<1024, 256, 0, stream>>>(Wo, wob,             1048576 / 4);
  bias_cat_kernel<<<12, 256, 0, stream>>>(bq, bk, bv, bcat);
  gate_kernel<<<256, 256, 0, stream>>>(x, Wg, bg, gateb);

  // fused QKV projection: [4096,1024] @ [3072,1024]^T
  gemm_bt<1><<<dim3(24, 32), 256, 0, stream>>>(xb, wqkv, bcat, qkv, MTOT, 3072, 1024);

  // RoPE (q,k) + V transpose
  rope_kernel<<<8192, 256, 0, stream>>>(qkv, cosb, sinb, q_r, k_r);
  vtrans_kernel<<<dim3(32, 32), 256, 0, stream>>>(qkv, v_t);

  // windowed causal flash attention + gate (barrier-free)
  attn_kernel<<<1024, 256, 0, stream>>>(q_r, k_r, v_t, gateb, attn);

  // output projection: [4096,1024] @ [1024,1024]^T + bo -> f32 out
  gemm_bt<0><<<dim3(8, 32), 256, 0, stream>>>(attn, wob, bo, out, MTOT, 1024, 1024);
}

// Round 3
// 162.890 us; speedup vs baseline: 1.3542x; 1.3424x over previous
//
#include <hip/hip_runtime.h>

#define DIMM 1024
#define NHEADS 16
#define HDIM 64
#define WIN 1024
#define GATEIN 20
#define BB 2
#define TT 2048
#define MTOT (BB*TT)   // 4096

typedef __attribute__((ext_vector_type(8))) short short8;
typedef __attribute__((ext_vector_type(4))) float f32x4;
typedef __attribute__((ext_vector_type(16))) float f32x16;
typedef const __attribute__((address_space(1))) void gvoid_t;
typedef __attribute__((address_space(3))) void lvoid_t;

__device__ __forceinline__ unsigned short f2b(float f) {
  union { float f; unsigned u; } c; c.f = f;
  unsigned u = c.u + 0x7fffu + ((c.u >> 16) & 1u);
  return (unsigned short)(u >> 16);
}
__device__ __forceinline__ float b2f(unsigned short s) {
  union { unsigned u; float f; } c; c.u = ((unsigned)s) << 16;
  return c.f;
}
__device__ __forceinline__ unsigned cvt_pk_bf16(float lo, float hi) {
  unsigned r;
  asm("v_cvt_pk_bf16_f32 %0, %1, %2" : "=v"(r) : "v"(lo), "v"(hi));
  return r;
}

// ---------------- conversion f32 -> bf16 (4 elems/thread) ----------------
__global__ void cvt_bf16_kernel(const float* __restrict__ src,
                                unsigned short* __restrict__ dst, int n4) {
  int i = blockIdx.x * blockDim.x + threadIdx.x;
  if (i >= n4) return;
  float4 v = ((const float4*)src)[i];
  union { unsigned short s[4]; uint2 u; } o;
  o.s[0] = f2b(v.x); o.s[1] = f2b(v.y); o.s[2] = f2b(v.z); o.s[3] = f2b(v.w);
  *(uint2*)(dst + (size_t)i * 4) = o.u;
}

// ---------------- bias concat [bq|bk|bv] -> 3072 ----------------
__global__ void bias_cat_kernel(const float* __restrict__ bq, const float* __restrict__ bk,
                                const float* __restrict__ bv, float* __restrict__ out) {
  int i = blockIdx.x * blockDim.x + threadIdx.x;
  if (i >= 3072) return;
  out[i] = (i < 1024) ? bq[i] : (i < 2048) ? bk[i - 1024] : bv[i - 2048];
}

// ---------------- gate = sigmoid(x[:, :20] @ Wg^T + bg), [M][H] f32 ----------------
__global__ void gate_kernel(const float* __restrict__ x, const float* __restrict__ Wg,
                            const float* __restrict__ bg, float* __restrict__ gate) {
  int i = blockIdx.x * blockDim.x + threadIdx.x;   // M*H
  if (i >= MTOT * NHEADS) return;
  int h = i & 15;
  int m = i >> 4;
  const float* xr = x + (size_t)m * DIMM;
  const float* wr = Wg + h * GATEIN;
  float z = bg[h];
#pragma unroll
  for (int g = 0; g < GATEIN; ++g) z += xr[g] * wr[g];
  gate[i] = 1.f / (1.f + __expf(-z));
}

// ---------------- GEMM: C[M,N] = A[M,K] @ Bw[N,K]^T + bias, bf16 in, f32 acc ----------------
template<int OUTBF>
__global__ __launch_bounds__(256) void gemm_bt(const unsigned short* __restrict__ A,
                                               const unsigned short* __restrict__ Bw,
                                               const float* __restrict__ bias,
                                               void* __restrict__ Cout,
                                               int M, int N, int K) {
  __shared__ __align__(16) unsigned short As[128 * 32];
  __shared__ __align__(16) unsigned short Bs[128 * 32];
  const int tid = threadIdx.x;
  const int lane = tid & 63, wid = tid >> 6;
  const int g = lane >> 4, r16 = lane & 15;
  const int m0 = blockIdx.y * 128, n0 = blockIdx.x * 128;
  const int wr = (wid >> 1) * 64, wc = (wid & 1) * 64;
  const int wbase = wid * 64;

  f32x4 acc[4][4];
#pragma unroll
  for (int i = 0; i < 4; ++i)
#pragma unroll
    for (int j = 0; j < 4; ++j) acc[i][j] = (f32x4){0.f, 0.f, 0.f, 0.f};

  for (int k0 = 0; k0 < K; k0 += 32) {
#pragma unroll
    for (int j = 0; j < 2; ++j) {
      int sbase = j * 256 + wbase;
      int s = sbase + lane;
      const unsigned short* gA = A + (size_t)(m0 + (s >> 2)) * K + k0 + (s & 3) * 8;
      __builtin_amdgcn_global_load_lds((gvoid_t*)gA, (lvoid_t*)((char*)As + sbase * 16), 16, 0, 0);
      const unsigned short* gB = Bw + (size_t)(n0 + (s >> 2)) * K + k0 + (s & 3) * 8;
      __builtin_amdgcn_global_load_lds((gvoid_t*)gB, (lvoid_t*)((char*)Bs + sbase * 16), 16, 0, 0);
    }
    __syncthreads();
    short8 af[4], bf[4];
#pragma unroll
    for (int mf = 0; mf < 4; ++mf)
      af[mf] = *(const short8*)(As + (wr + mf * 16 + r16) * 32 + g * 8);
#pragma unroll
    for (int nf = 0; nf < 4; ++nf)
      bf[nf] = *(const short8*)(Bs + (wc + nf * 16 + r16) * 32 + g * 8);
#pragma unroll
    for (int mf = 0; mf < 4; ++mf)
#pragma unroll
      for (int nf = 0; nf < 4; ++nf)
        acc[mf][nf] = __builtin_amdgcn_mfma_f32_16x16x32_bf16(af[mf], bf[nf], acc[mf][nf], 0, 0, 0);
    __syncthreads();
  }
#pragma unroll
  for (int mf = 0; mf < 4; ++mf)
#pragma unroll
    for (int nf = 0; nf < 4; ++nf)
#pragma unroll
      for (int rr = 0; rr < 4; ++rr) {
        int m = m0 + wr + mf * 16 + g * 4 + rr;
        int n = n0 + wc + nf * 16 + r16;
        float v = acc[mf][nf][rr] + bias[n];
        if (OUTBF) ((unsigned short*)Cout)[(size_t)m * N + n] = f2b(v);
        else       ((float*)Cout)[(size_t)m * N + n] = v;
      }
}

// ---------------- RoPE + relayout: qkv_cat [M][3072] -> q_r/k_r [B*H][T][64] ----------------
// NOTE: 1/sqrt(HDIM)=0.125 is folded into q (exact exponent shift in bf16)
__global__ void rope_kernel(const unsigned short* __restrict__ qkv,
                            const float* __restrict__ cosb, const float* __restrict__ sinb,
                            unsigned short* __restrict__ qr, unsigned short* __restrict__ kr) {
  int i = blockIdx.x * blockDim.x + threadIdx.x;   // M*H*32
  if (i >= MTOT * NHEADS * 32) return;
  int d = i & 31;
  int h = (i >> 5) & 15;
  int m = i >> 9;             // b*T + t
  int t = m & (TT - 1);
  int b = m >> 11;
  const unsigned short* row = qkv + (size_t)m * 3072;
  float c = cosb[t * 32 + d], s = sinb[t * 32 + d];
  float q1 = b2f(row[h * 64 + d]),        q2 = b2f(row[h * 64 + d + 32]);
  float k1 = b2f(row[1024 + h * 64 + d]), k2 = b2f(row[1024 + h * 64 + d + 32]);
  size_t o = ((size_t)(b * NHEADS + h) * TT + t) * HDIM + d;
  qr[o]      = f2b((q1 * c - q2 * s) * 0.125f);
  qr[o + 32] = f2b((q1 * s + q2 * c) * 0.125f);
  kr[o]      = f2b(k1 * c - k2 * s);
  kr[o + 32] = f2b(k1 * s + k2 * c);
}

// ---------------- V transpose: qkv[:,2048:3072] -> vt [B*H][64 d][2048 t] ----------------
__global__ __launch_bounds__(256) void vtrans_kernel(const unsigned short* __restrict__ qkv,
                                                     unsigned short* __restrict__ vt) {
  __shared__ unsigned short tile[64][66];
  const int t0 = blockIdx.x * 64;
  const int bh = blockIdx.y;
  const int b = bh >> 4, h = bh & 15;
  const int tid = threadIdx.x;
  const int r = tid >> 2;
  const int c0 = (tid & 3) * 16;
  {
    const unsigned short* src = qkv + (size_t)(b * TT + t0 + r) * 3072 + 2048 + h * 64 + c0;
    short8 v0 = *(const short8*)src;
    short8 v1 = *(const short8*)(src + 8);
#pragma unroll
    for (int j = 0; j < 8; ++j) {
      tile[r][c0 + j] = (unsigned short)v0[j];
      tile[r][c0 + 8 + j] = (unsigned short)v1[j];
    }
  }
  __syncthreads();
  {
    const int d = tid >> 2;
    const int tc = (tid & 3) * 16;
    short8 o0, o1;
#pragma unroll
    for (int j = 0; j < 8; ++j) {
      o0[j] = (short)tile[tc + j][d];
      o1[j] = (short)tile[tc + 8 + j][d];
    }
    unsigned short* dst = vt + ((size_t)bh * HDIM + d) * TT + t0 + tc;
    *(short8*)dst = o0;
    *(short8*)(dst + 8) = o1;
  }
}

// ---------------- flash attention: swapped QK^T (32x32), in-register softmax ----------------
// Per wave: 32 q-rows. S^T = mfma(K,Q) -> lane holds S[q=lane&31][16 keys].
// O^T = V^T @ P^T -> acc cols = q = lane&31 (softmax state & rescale lane-local).
// No LDS. P->bf16 via cvt_pk + permlane32_swap (T12).
__global__ __launch_bounds__(256) void attn_kernel(const unsigned short* __restrict__ qr,
                                                   const unsigned short* __restrict__ kr,
                                                   const unsigned short* __restrict__ vt,
                                                   const float* __restrict__ gate,
                                                   unsigned short* __restrict__ attn_out) {
  const int tid = threadIdx.x;
  const int lane = tid & 63, wid = tid >> 6;
  const int l31 = lane & 31, hi = lane >> 5;

  // XCD swizzle: 512 blocks, 8 XCDs; each XCD owns 4 bh (K/V+Q ~3MB < 4MB L2)
  const int fid = blockIdx.x;
  const int idx = fid >> 3;                 // 0..63
  const int bh = (fid & 7) * 4 + (idx >> 4);
  const int qt = (idx & 15) * 4 + wid;      // 0..63
  const int q0 = qt * 32;
  const int b = bh >> 4, h = bh & 15;
  const size_t base  = (size_t)bh * TT * HDIM;
  const size_t vbase = (size_t)bh * HDIM * TT;

  const int q = q0 + l31;                   // this lane's q row

  // Q B-frags (col=q=lane&31, k(d) = st*16 + hi*8 + j), loaded once
  short8 qf[4];
#pragma unroll
  for (int st = 0; st < 4; ++st)
    qf[st] = *(const short8*)(qr + base + (size_t)q * HDIM + st * 16 + hi * 8);

  f32x16 o0, o1;
#pragma unroll
  for (int r = 0; r < 16; ++r) { o0[r] = 0.f; o1[r] = 0.f; }
  float mrun = -1e30f, lrun = 0.f;

  int kv_lo = q0 - WIN;
  if (kv_lo < 0) kv_lo = 0;
  const int kv_hi = q0 + 32;

  for (int kv = kv_lo; kv < kv_hi; kv += 32) {
    // ---- S^T = K @ Q^T : A row = key = kv+l31, split into 2 indep chains
    f32x16 sA, sB;
#pragma unroll
    for (int r = 0; r < 16; ++r) { sA[r] = 0.f; sB[r] = 0.f; }
    const unsigned short* krow = kr + base + (size_t)(kv + l31) * HDIM + hi * 8;
    sA = __builtin_amdgcn_mfma_f32_32x32x16_bf16(*(const short8*)(krow),      qf[0], sA, 0, 0, 0);
    sB = __builtin_amdgcn_mfma_f32_32x32x16_bf16(*(const short8*)(krow + 16), qf[1], sB, 0, 0, 0);
    sA = __builtin_amdgcn_mfma_f32_32x32x16_bf16(*(const short8*)(krow + 32), qf[2], sA, 0, 0, 0);
    sB = __builtin_amdgcn_mfma_f32_32x32x16_bf16(*(const short8*)(krow + 48), qf[3], sB, 0, 0, 0);

    // ---- V^T A-frags for PV (issue early; independent of softmax)
    const unsigned short* vrow = vt + vbase + (size_t)l31 * TT + kv + hi * 8;
    short8 vf00 = *(const short8*)(vrow);                 // d 0..31, keys 0..15
    short8 vf01 = *(const short8*)(vrow + 16);            // d 0..31, keys 16..31
    short8 vf10 = *(const short8*)(vrow + 32 * TT);       // d 32..63, keys 0..15
    short8 vf11 = *(const short8*)(vrow + 32 * TT + 16);  // d 32..63, keys 16..31

    // ---- mask + row-max (key_r = (r&3) + 8*(r>>2) + 4*hi, q fixed per lane)
    float p[16];
    float lm = -1e30f;
#pragma unroll
    for (int r = 0; r < 16; ++r) {
      int key = kv + (r & 3) + 8 * (r >> 2) + 4 * hi;
      float s = sA[r] + sB[r];
      bool valid = (key <= q) && (key + WIN >= q);
      s = valid ? s : -1e30f;
      p[r] = s;
      lm = fmaxf(lm, s);
    }
    lm = fmaxf(lm, __shfl_xor(lm, 32));
    float mnew = fmaxf(mrun, lm);
    float scf = __expf(mrun - mnew);
    mrun = mnew;

    float rs = 0.f;
#pragma unroll
    for (int r = 0; r < 16; ++r) {
      float e = __expf(p[r] - mnew);
      e = (p[r] > -1e29f) ? e : 0.f;
      p[r] = e;
      rs += e;
    }
    rs += __shfl_xor(rs, 32);
    lrun = lrun * scf + rs;
#pragma unroll
    for (int r = 0; r < 16; ++r) { o0[r] *= scf; o1[r] *= scf; }

    // ---- P -> bf16 B-frags (col=q): cvt_pk + permlane32_swap (T12)
    unsigned w0 = cvt_pk_bf16(p[0],  p[1]),  w1 = cvt_pk_bf16(p[2],  p[3]);
    unsigned w2 = cvt_pk_bf16(p[4],  p[5]),  w3 = cvt_pk_bf16(p[6],  p[7]);
    unsigned w4 = cvt_pk_bf16(p[8],  p[9]),  w5 = cvt_pk_bf16(p[10], p[11]);
    unsigned w6 = cvt_pk_bf16(p[12], p[13]), w7 = cvt_pk_bf16(p[14], p[15]);
    auto s1 = __builtin_amdgcn_permlane32_swap(w0, w2, false, false);
    auto s2 = __builtin_amdgcn_permlane32_swap(w1, w3, false, false);
    auto s3 = __builtin_amdgcn_permlane32_swap(w4, w6, false, false);
    auto s4 = __builtin_amdgcn_permlane32_swap(w5, w7, false, false);
    union { unsigned u[4]; short8 s; } pf0, pf1;
    pf0.u[0] = s1[0]; pf0.u[1] = s2[0]; pf0.u[2] = s1[1]; pf0.u[3] = s2[1];
    pf1.u[0] = s3[0]; pf1.u[1] = s4[0]; pf1.u[2] = s3[1]; pf1.u[3] = s4[1];

    // ---- O^T += V^T @ P^T (2 indep acc chains)
    o0 = __builtin_amdgcn_mfma_f32_32x32x16_bf16(vf00, pf0.s, o0, 0, 0, 0);
    o1 = __builtin_amdgcn_mfma_f32_32x32x16_bf16(vf10, pf0.s, o1, 0, 0, 0);
    o0 = __builtin_amdgcn_mfma_f32_32x32x16_bf16(vf01, pf1.s, o0, 0, 0, 0);
    o1 = __builtin_amdgcn_mfma_f32_32x32x16_bf16(vf11, pf1.s, o1, 0, 0, 0);
  }

  // ---- epilogue: O^T[d][q] -> attn_out[(b*T+q)*1024 + h*64 + d], gate/normalize
  float gv = gate[((size_t)b * TT + q) * NHEADS + h];
  float inv = gv / lrun;
  unsigned short* orow = attn_out + ((size_t)b * TT + q) * DIMM + h * HDIM;
#pragma unroll
  for (int a2 = 0; a2 < 4; ++a2) {
    int d0 = a2 * 8 + hi * 4;
    union { unsigned short s[4]; uint2 u; } x0, x1;
#pragma unroll
    for (int c = 0; c < 4; ++c) {
      x0.s[c] = f2b(o0[a2 * 4 + c] * inv);
      x1.s[c] = f2b(o1[a2 * 4 + c] * inv);
    }
    *(uint2*)(orow + d0) = x0.u;
    *(uint2*)(orow + 32 + d0) = x1.u;
  }
}

// ---------------- workspace layout (bytes) ----------------
#define OFF_XB    ((size_t)0)
#define OFF_WQKV  ((size_t)8388608)
#define OFF_WO    ((size_t)14680064)
#define OFF_BCAT  ((size_t)16777216)
#define OFF_QKV   ((size_t)16793600)
#define OFF_QR    ((size_t)41959424)
#define OFF_KR    ((size_t)50348032)
#define OFF_VT    ((size_t)58736640)
#define OFF_ATTN  ((size_t)67125248)
#define OFF_GATE  ((size_t)75513856)

extern "C" void kernel_launch(void* const* d_in, const int* in_sizes, int n_in,
                              void* d_out, int out_size, void* d_ws, size_t ws_size,
                              hipStream_t stream) {
  const float* x    = (const float*)d_in[0];
  const float* Wq   = (const float*)d_in[1];
  const float* bq   = (const float*)d_in[2];
  const float* Wk   = (const float*)d_in[3];
  const float* bk   = (const float*)d_in[4];
  const float* Wv   = (const float*)d_in[5];
  const float* bv   = (const float*)d_in[6];
  const float* Wo   = (const float*)d_in[7];
  const float* bo   = (const float*)d_in[8];
  const float* Wg   = (const float*)d_in[9];
  const float* bg   = (const float*)d_in[10];
  const float* cosb = (const float*)d_in[11];
  const float* sinb = (const float*)d_in[12];
  float* out = (float*)d_out;
  char* ws = (char*)d_ws;

  unsigned short* xb    = (unsigned short*)(ws + OFF_XB);
  unsigned short* wqkv  = (unsigned short*)(ws + OFF_WQKV);
  unsigned short* wob   = (unsigned short*)(ws + OFF_WO);
  float*          bcat  = (float*)(ws + OFF_BCAT);
  unsigned short* qkv   = (unsigned short*)(ws + OFF_QKV);
  unsigned short* q_r   = (unsigned short*)(ws + OFF_QR);
  unsigned short* k_r   = (unsigned short*)(ws + OFF_KR);
  unsigned short* v_t   = (unsigned short*)(ws + OFF_VT);
  unsigned short* attn  = (unsigned short*)(ws + OFF_ATTN);
  float*          gateb = (float*)(ws + OFF_GATE);

  cvt_bf16_kernel<<<4096, 256, 0, stream>>>(x, xb, 4194304 / 4);
  cvt_bf16_kernel<<<1024, 256, 0, stream>>>(Wq, wqkv,            1048576 / 4);
  cvt_bf16_kernel<<<1024, 256, 0, stream>>>(Wk, wqkv + 1048576,  1048576 / 4);
  cvt_bf16_kernel<<<1024, 256, 0, stream>>>(Wv, wqkv + 2097152,  1048576 / 4);
  cvt_bf16_kernel<<<1024, 256, 0, stream>>>(Wo, wob,             1048576 / 4);
  bias_cat_kernel<<<12, 256, 0, stream>>>(bq, bk, bv, bcat);
  gate_kernel<<<256, 256, 0, stream>>>(x, Wg, bg, gateb);

  // fused QKV projection: [4096,1024] @ [3072,1024]^T
  gemm_bt<1><<<dim3(24, 32), 256, 0, stream>>>(xb, wqkv, bcat, qkv, MTOT, 3072, 1024);

  // RoPE (q scaled by 0.125) + V transpose
  rope_kernel<<<8192, 256, 0, stream>>>(qkv, cosb, sinb, q_r, k_r);
  vtrans_kernel<<<dim3(32, 32), 256, 0, stream>>>(qkv, v_t);

  // windowed causal flash attention + gate (LDS-free, in-register softmax)
  attn_kernel<<<512, 256, 0, stream>>>(q_r, k_r, v_t, gateb, attn);

  // output projection: [4096,1024] @ [1024,1024]^T + bo -> f32 out
  gemm_bt<0><<<dim3(8, 32), 256, 0, stream>>>(attn, wob, bo, out, MTOT, 1024, 1024);
}

// Round 4
// 161.763 us; speedup vs baseline: 1.3637x; 1.0070x over previous
//
#include <hip/hip_runtime.h>

#define DIMM 1024
#define NHEADS 16
#define HDIM 64
#define WIN 1024
#define GATEIN 20
#define BB 2
#define TT 2048
#define MTOT (BB*TT)   // 4096

typedef __attribute__((ext_vector_type(8))) short short8;
typedef __attribute__((ext_vector_type(4))) float f32x4;
typedef __attribute__((ext_vector_type(16))) float f32x16;
typedef const __attribute__((address_space(1))) void gvoid_t;
typedef __attribute__((address_space(3))) void lvoid_t;

__device__ __forceinline__ unsigned short f2b(float f) {
  union { float f; unsigned u; } c; c.f = f;
  unsigned u = c.u + 0x7fffu + ((c.u >> 16) & 1u);
  return (unsigned short)(u >> 16);
}
__device__ __forceinline__ float b2f(unsigned short s) {
  union { unsigned u; float f; } c; c.u = ((unsigned)s) << 16;
  return c.f;
}
__device__ __forceinline__ unsigned cvt_pk_bf16(float lo, float hi) {
  unsigned r;
  asm("v_cvt_pk_bf16_f32 %0, %1, %2" : "=v"(r) : "v"(lo), "v"(hi));
  return r;
}
// cross-half (lane ^ 32) reductions via permlane32_swap (VALU, no DS)
__device__ __forceinline__ float xmax32(float x) {
  union { float f; unsigned u; } c; c.f = x;
  auto pr = __builtin_amdgcn_permlane32_swap(c.u, c.u, false, false);
  union { unsigned u; float f; } a, b; a.u = pr[0]; b.u = pr[1];
  return fmaxf(a.f, b.f);
}
__device__ __forceinline__ float xsum32(float x) {
  union { float f; unsigned u; } c; c.f = x;
  auto pr = __builtin_amdgcn_permlane32_swap(c.u, c.u, false, false);
  union { unsigned u; float f; } a, b; a.u = pr[0]; b.u = pr[1];
  return a.f + b.f;
}

// ---------------- conversion f32 -> bf16 (4 elems/thread) ----------------
__global__ void cvt_bf16_kernel(const float* __restrict__ src,
                                unsigned short* __restrict__ dst, int n4) {
  int i = blockIdx.x * blockDim.x + threadIdx.x;
  if (i >= n4) return;
  float4 v = ((const float4*)src)[i];
  union { unsigned short s[4]; uint2 u; } o;
  o.s[0] = f2b(v.x); o.s[1] = f2b(v.y); o.s[2] = f2b(v.z); o.s[3] = f2b(v.w);
  *(uint2*)(dst + (size_t)i * 4) = o.u;
}

// ---------------- bias concat [bq|bk|bv] -> 3072 ----------------
__global__ void bias_cat_kernel(const float* __restrict__ bq, const float* __restrict__ bk,
                                const float* __restrict__ bv, float* __restrict__ out) {
  int i = blockIdx.x * blockDim.x + threadIdx.x;
  if (i >= 3072) return;
  out[i] = (i < 1024) ? bq[i] : (i < 2048) ? bk[i - 1024] : bv[i - 2048];
}

// ---------------- gate = sigmoid(x[:, :20] @ Wg^T + bg), [M][H] f32 ----------------
__global__ void gate_kernel(const float* __restrict__ x, const float* __restrict__ Wg,
                            const float* __restrict__ bg, float* __restrict__ gate) {
  int i = blockIdx.x * blockDim.x + threadIdx.x;   // M*H
  if (i >= MTOT * NHEADS) return;
  int h = i & 15;
  int m = i >> 4;
  const float* xr = x + (size_t)m * DIMM;
  const float* wr = Wg + h * GATEIN;
  float z = bg[h];
#pragma unroll
  for (int g = 0; g < GATEIN; ++g) z += xr[g] * wr[g];
  gate[i] = 1.f / (1.f + __expf(-z));
}

// ---------------- GEMM: C[M,N] = A[M,K] @ Bw[N,K]^T + bias, bf16 in, f32 acc ----------------
template<int OUTBF>
__global__ __launch_bounds__(256) void gemm_bt(const unsigned short* __restrict__ A,
                                               const unsigned short* __restrict__ Bw,
                                               const float* __restrict__ bias,
                                               void* __restrict__ Cout,
                                               int M, int N, int K) {
  __shared__ __align__(16) unsigned short As[128 * 32];
  __shared__ __align__(16) unsigned short Bs[128 * 32];
  const int tid = threadIdx.x;
  const int lane = tid & 63, wid = tid >> 6;
  const int g = lane >> 4, r16 = lane & 15;
  const int m0 = blockIdx.y * 128, n0 = blockIdx.x * 128;
  const int wr = (wid >> 1) * 64, wc = (wid & 1) * 64;
  const int wbase = wid * 64;

  f32x4 acc[4][4];
#pragma unroll
  for (int i = 0; i < 4; ++i)
#pragma unroll
    for (int j = 0; j < 4; ++j) acc[i][j] = (f32x4){0.f, 0.f, 0.f, 0.f};

  for (int k0 = 0; k0 < K; k0 += 32) {
#pragma unroll
    for (int j = 0; j < 2; ++j) {
      int sbase = j * 256 + wbase;
      int s = sbase + lane;
      const unsigned short* gA = A + (size_t)(m0 + (s >> 2)) * K + k0 + (s & 3) * 8;
      __builtin_amdgcn_global_load_lds((gvoid_t*)gA, (lvoid_t*)((char*)As + sbase * 16), 16, 0, 0);
      const unsigned short* gB = Bw + (size_t)(n0 + (s >> 2)) * K + k0 + (s & 3) * 8;
      __builtin_amdgcn_global_load_lds((gvoid_t*)gB, (lvoid_t*)((char*)Bs + sbase * 16), 16, 0, 0);
    }
    __syncthreads();
    short8 af[4], bf[4];
#pragma unroll
    for (int mf = 0; mf < 4; ++mf)
      af[mf] = *(const short8*)(As + (wr + mf * 16 + r16) * 32 + g * 8);
#pragma unroll
    for (int nf = 0; nf < 4; ++nf)
      bf[nf] = *(const short8*)(Bs + (wc + nf * 16 + r16) * 32 + g * 8);
#pragma unroll
    for (int mf = 0; mf < 4; ++mf)
#pragma unroll
      for (int nf = 0; nf < 4; ++nf)
        acc[mf][nf] = __builtin_amdgcn_mfma_f32_16x16x32_bf16(af[mf], bf[nf], acc[mf][nf], 0, 0, 0);
    __syncthreads();
  }
#pragma unroll
  for (int mf = 0; mf < 4; ++mf)
#pragma unroll
    for (int nf = 0; nf < 4; ++nf)
#pragma unroll
      for (int rr = 0; rr < 4; ++rr) {
        int m = m0 + wr + mf * 16 + g * 4 + rr;
        int n = n0 + wc + nf * 16 + r16;
        float v = acc[mf][nf][rr] + bias[n];
        if (OUTBF) ((unsigned short*)Cout)[(size_t)m * N + n] = f2b(v);
        else       ((float*)Cout)[(size_t)m * N + n] = v;
      }
}

// ---------------- RoPE + relayout: qkv_cat [M][3072] -> q_r/k_r [B*H][T][64] ----------------
// q is scaled by 0.125 * log2(e): attention scores come out in log2 domain.
#define QSCALE (0.125f * 1.4426950408889634f)
__global__ void rope_kernel(const unsigned short* __restrict__ qkv,
                            const float* __restrict__ cosb, const float* __restrict__ sinb,
                            unsigned short* __restrict__ qr, unsigned short* __restrict__ kr) {
  int i = blockIdx.x * blockDim.x + threadIdx.x;   // M*H*32
  if (i >= MTOT * NHEADS * 32) return;
  int d = i & 31;
  int h = (i >> 5) & 15;
  int m = i >> 9;             // b*T + t
  int t = m & (TT - 1);
  int b = m >> 11;
  const unsigned short* row = qkv + (size_t)m * 3072;
  float c = cosb[t * 32 + d], s = sinb[t * 32 + d];
  float q1 = b2f(row[h * 64 + d]),        q2 = b2f(row[h * 64 + d + 32]);
  float k1 = b2f(row[1024 + h * 64 + d]), k2 = b2f(row[1024 + h * 64 + d + 32]);
  size_t o = ((size_t)(b * NHEADS + h) * TT + t) * HDIM + d;
  qr[o]      = f2b((q1 * c - q2 * s) * QSCALE);
  qr[o + 32] = f2b((q1 * s + q2 * c) * QSCALE);
  kr[o]      = f2b(k1 * c - k2 * s);
  kr[o + 32] = f2b(k1 * s + k2 * c);
}

// ---------------- V transpose: qkv[:,2048:3072] -> vt [B*H][64 d][2048 t] ----------------
__global__ __launch_bounds__(256) void vtrans_kernel(const unsigned short* __restrict__ qkv,
                                                     unsigned short* __restrict__ vt) {
  __shared__ unsigned short tile[64][66];
  const int t0 = blockIdx.x * 64;
  const int bh = blockIdx.y;
  const int b = bh >> 4, h = bh & 15;
  const int tid = threadIdx.x;
  const int r = tid >> 2;
  const int c0 = (tid & 3) * 16;
  {
    const unsigned short* src = qkv + (size_t)(b * TT + t0 + r) * 3072 + 2048 + h * 64 + c0;
    short8 v0 = *(const short8*)src;
    short8 v1 = *(const short8*)(src + 8);
#pragma unroll
    for (int j = 0; j < 8; ++j) {
      tile[r][c0 + j] = (unsigned short)v0[j];
      tile[r][c0 + 8 + j] = (unsigned short)v1[j];
    }
  }
  __syncthreads();
  {
    const int d = tid >> 2;
    const int tc = (tid & 3) * 16;
    short8 o0, o1;
#pragma unroll
    for (int j = 0; j < 8; ++j) {
      o0[j] = (short)tile[tc + j][d];
      o1[j] = (short)tile[tc + 8 + j][d];
    }
    unsigned short* dst = vt + ((size_t)bh * HDIM + d) * TT + t0 + tc;
    *(short8*)dst = o0;
    *(short8*)(dst + 8) = o1;
  }
}

// ---------------- flash attention: swapped QK^T (32x32), lane-local softmax ----------------
// 1 wave per block (2048 blocks). Per wave: 32 q-rows, KVBLK=32.
// exp2 domain, defer-max (THR=8 -> P<=256), mask-peeled steps, K prefetch ping-pong.
__global__ __launch_bounds__(64) void attn_kernel(const unsigned short* __restrict__ qr,
                                                  const unsigned short* __restrict__ kr,
                                                  const unsigned short* __restrict__ vt,
                                                  const float* __restrict__ gate,
                                                  unsigned short* __restrict__ attn_out) {
  const int lane = threadIdx.x;
  const int l31 = lane & 31, hi = lane >> 5;

  // XCD swizzle: 2048 blocks; each XCD owns 4 bh (Q+K+V ~3MB < 4MB L2)
  const int fid = blockIdx.x;
  const int idx = fid >> 3;                 // 0..255
  const int bh = (fid & 7) * 4 + (idx >> 6);
  const int q0 = (idx & 63) * 32;
  const int b = bh >> 4, h = bh & 15;
  const unsigned short* kptr = kr + (size_t)bh * TT * HDIM;
  const unsigned short* vptr = vt + (size_t)bh * HDIM * TT;
  const int q = q0 + l31;                   // this lane's q row

  // Q B-frags (col=q, k(d) = st*16 + hi*8 + j)
  short8 qf[4];
#pragma unroll
  for (int st = 0; st < 4; ++st)
    qf[st] = *(const short8*)(qr + (size_t)bh * TT * HDIM + (size_t)q * HDIM + st * 16 + hi * 8);

  f32x16 SZERO;
#pragma unroll
  for (int r = 0; r < 16; ++r) SZERO[r] = 0.f;
  f32x16 o0 = SZERO, o1 = SZERO;
  float mrun = -1e30f, lrun = 0.f;

  int kv_lo = q0 - WIN;
  if (kv_lo < 0) kv_lo = 0;
  const int kv_hi = q0 + 32;

  // step body: S from kcur, prefetch K(next) into knext, V loads, softmax, PV
  auto doStep = [&](int kv, short8 (&kcur)[4], short8 (&knext)[4]) {
    // single dependent S chain seeded from loop-invariant zero regs (no per-step movs)
    f32x16 s;
    s = __builtin_amdgcn_mfma_f32_32x32x16_bf16(kcur[0], qf[0], SZERO, 0, 0, 0);
    s = __builtin_amdgcn_mfma_f32_32x32x16_bf16(kcur[1], qf[1], s, 0, 0, 0);
    s = __builtin_amdgcn_mfma_f32_32x32x16_bf16(kcur[2], qf[2], s, 0, 0, 0);
    s = __builtin_amdgcn_mfma_f32_32x32x16_bf16(kcur[3], qf[3], s, 0, 0, 0);

    // prefetch next K (clamped re-load of current on last step: always in-bounds)
    const int kvn = (kv + 32 < kv_hi) ? kv + 32 : kv;
    const unsigned short* krow = kptr + (size_t)(kvn + l31) * HDIM + hi * 8;
    knext[0] = *(const short8*)(krow);
    knext[1] = *(const short8*)(krow + 16);
    knext[2] = *(const short8*)(krow + 32);
    knext[3] = *(const short8*)(krow + 48);

    // V A-frags for this step (needed only after softmax -> latency hidden)
    const unsigned short* vrow = vptr + (size_t)l31 * TT + kv + hi * 8;
    short8 vf00 = *(const short8*)(vrow);
    short8 vf01 = *(const short8*)(vrow + 16);
    short8 vf10 = *(const short8*)(vrow + 32 * TT);
    short8 vf11 = *(const short8*)(vrow + 32 * TT + 16);

    // masks only on peeled steps (wave-uniform branches)
    float sv[16];
    if (kv == q0) {            // causal (last step)
#pragma unroll
      for (int r = 0; r < 16; ++r) {
        int key = kv + (r & 3) + 8 * (r >> 2) + 4 * hi;
        sv[r] = (key <= q) ? s[r] : -1e30f;
      }
    } else if (q0 >= WIN && kv == kv_lo) {   // window edge (first step)
#pragma unroll
      for (int r = 0; r < 16; ++r) {
        int key = kv + (r & 3) + 8 * (r >> 2) + 4 * hi;
        sv[r] = (key + WIN >= q) ? s[r] : -1e30f;
      }
    } else {
#pragma unroll
      for (int r = 0; r < 16; ++r) sv[r] = s[r];
    }

    // row-max: depth-4 tree + cross-half swap
    float a0 = fmaxf(sv[0], sv[1]),   a1 = fmaxf(sv[2], sv[3]);
    float a2 = fmaxf(sv[4], sv[5]),   a3 = fmaxf(sv[6], sv[7]);
    float a4 = fmaxf(sv[8], sv[9]),   a5 = fmaxf(sv[10], sv[11]);
    float a6 = fmaxf(sv[12], sv[13]), a7 = fmaxf(sv[14], sv[15]);
    float b0 = fmaxf(a0, a1), b1 = fmaxf(a2, a3), b2 = fmaxf(a4, a5), b3 = fmaxf(a6, a7);
    float lm = fmaxf(fmaxf(b0, b1), fmaxf(b2, b3));
    lm = xmax32(lm);

    // defer-max: rescale only when max grows by >8 (log2 units -> P <= 256)
    if (!__all(lm - mrun <= 8.f)) {
      float mnew = fmaxf(mrun, lm);
      float scf = __builtin_exp2f(mrun - mnew);
      mrun = mnew;
      lrun *= scf;
#pragma unroll
      for (int r = 0; r < 16; ++r) { o0[r] *= scf; o1[r] *= scf; }
    }

    // P = exp2(sv - mrun); masked entries underflow to 0
    float pv[16];
#pragma unroll
    for (int r = 0; r < 16; ++r) pv[r] = __builtin_exp2f(sv[r] - mrun);
    float c0 = (pv[0] + pv[1]) + (pv[2] + pv[3]);
    float c1 = (pv[4] + pv[5]) + (pv[6] + pv[7]);
    float c2 = (pv[8] + pv[9]) + (pv[10] + pv[11]);
    float c3 = (pv[12] + pv[13]) + (pv[14] + pv[15]);
    float rs = (c0 + c1) + (c2 + c3);
    lrun += xsum32(rs);

    // P -> bf16 B-frags: cvt_pk + permlane32_swap (T12)
    unsigned w0 = cvt_pk_bf16(pv[0],  pv[1]),  w1 = cvt_pk_bf16(pv[2],  pv[3]);
    unsigned w2 = cvt_pk_bf16(pv[4],  pv[5]),  w3 = cvt_pk_bf16(pv[6],  pv[7]);
    unsigned w4 = cvt_pk_bf16(pv[8],  pv[9]),  w5 = cvt_pk_bf16(pv[10], pv[11]);
    unsigned w6 = cvt_pk_bf16(pv[12], pv[13]), w7 = cvt_pk_bf16(pv[14], pv[15]);
    auto s1 = __builtin_amdgcn_permlane32_swap(w0, w2, false, false);
    auto s2 = __builtin_amdgcn_permlane32_swap(w1, w3, false, false);
    auto s3 = __builtin_amdgcn_permlane32_swap(w4, w6, false, false);
    auto s4 = __builtin_amdgcn_permlane32_swap(w5, w7, false, false);
    union { unsigned u[4]; short8 s8; } pf0, pf1;
    pf0.u[0] = s1[0]; pf0.u[1] = s2[0]; pf0.u[2] = s1[1]; pf0.u[3] = s2[1];
    pf1.u[0] = s3[0]; pf1.u[1] = s4[0]; pf1.u[2] = s3[1]; pf1.u[3] = s4[1];

    // O^T += V^T @ P^T
    o0 = __builtin_amdgcn_mfma_f32_32x32x16_bf16(vf00, pf0.s8, o0, 0, 0, 0);
    o1 = __builtin_amdgcn_mfma_f32_32x32x16_bf16(vf10, pf0.s8, o1, 0, 0, 0);
    o0 = __builtin_amdgcn_mfma_f32_32x32x16_bf16(vf01, pf1.s8, o0, 0, 0, 0);
    o1 = __builtin_amdgcn_mfma_f32_32x32x16_bf16(vf11, pf1.s8, o1, 0, 0, 0);
  };

  short8 kA[4], kB[4];
  {
    const unsigned short* krow = kptr + (size_t)(kv_lo + l31) * HDIM + hi * 8;
    kA[0] = *(const short8*)(krow);
    kA[1] = *(const short8*)(krow + 16);
    kA[2] = *(const short8*)(krow + 32);
    kA[3] = *(const short8*)(krow + 48);
  }
  for (int kv = kv_lo; ; ) {
    doStep(kv, kA, kB);
    kv += 32; if (kv >= kv_hi) break;
    doStep(kv, kB, kA);
    kv += 32; if (kv >= kv_hi) break;
  }

  // epilogue: O^T[d][q] -> attn_out, gate/normalize
  float gv = gate[((size_t)b * TT + q) * NHEADS + h];
  float inv = gv / lrun;
  unsigned short* orow = attn_out + ((size_t)b * TT + q) * DIMM + h * HDIM;
#pragma unroll
  for (int a2 = 0; a2 < 4; ++a2) {
    int d0 = a2 * 8 + hi * 4;
    union { unsigned short s[4]; uint2 u; } x0, x1;
#pragma unroll
    for (int c = 0; c < 4; ++c) {
      x0.s[c] = f2b(o0[a2 * 4 + c] * inv);
      x1.s[c] = f2b(o1[a2 * 4 + c] * inv);
    }
    *(uint2*)(orow + d0) = x0.u;
    *(uint2*)(orow + 32 + d0) = x1.u;
  }
}

// ---------------- workspace layout (bytes) ----------------
#define OFF_XB    ((size_t)0)
#define OFF_WQKV  ((size_t)8388608)
#define OFF_WO    ((size_t)14680064)
#define OFF_BCAT  ((size_t)16777216)
#define OFF_QKV   ((size_t)16793600)
#define OFF_QR    ((size_t)41959424)
#define OFF_KR    ((size_t)50348032)
#define OFF_VT    ((size_t)58736640)
#define OFF_ATTN  ((size_t)67125248)
#define OFF_GATE  ((size_t)75513856)

extern "C" void kernel_launch(void* const* d_in, const int* in_sizes, int n_in,
                              void* d_out, int out_size, void* d_ws, size_t ws_size,
                              hipStream_t stream) {
  const float* x    = (const float*)d_in[0];
  const float* Wq   = (const float*)d_in[1];
  const float* bq   = (const float*)d_in[2];
  const float* Wk   = (const float*)d_in[3];
  const float* bk   = (const float*)d_in[4];
  const float* Wv   = (const float*)d_in[5];
  const float* bv   = (const float*)d_in[6];
  const float* Wo   = (const float*)d_in[7];
  const float* bo   = (const float*)d_in[8];
  const float* Wg   = (const float*)d_in[9];
  const float* bg   = (const float*)d_in[10];
  const float* cosb = (const float*)d_in[11];
  const float* sinb = (const float*)d_in[12];
  float* out = (float*)d_out;
  char* ws = (char*)d_ws;

  unsigned short* xb    = (unsigned short*)(ws + OFF_XB);
  unsigned short* wqkv  = (unsigned short*)(ws + OFF_WQKV);
  unsigned short* wob   = (unsigned short*)(ws + OFF_WO);
  float*          bcat  = (float*)(ws + OFF_BCAT);
  unsigned short* qkv   = (unsigned short*)(ws + OFF_QKV);
  unsigned short* q_r   = (unsigned short*)(ws + OFF_QR);
  unsigned short* k_r   = (unsigned short*)(ws + OFF_KR);
  unsigned short* v_t   = (unsigned short*)(ws + OFF_VT);
  unsigned short* attn  = (unsigned short*)(ws + OFF_ATTN);
  float*          gateb = (float*)(ws + OFF_GATE);

  cvt_bf16_kernel<<<4096, 256, 0, stream>>>(x, xb, 4194304 / 4);
  cvt_bf16_kernel<<<1024, 256, 0, stream>>>(Wq, wqkv,            1048576 / 4);
  cvt_bf16_kernel<<<1024, 256, 0, stream>>>(Wk, wqkv + 1048576,  1048576 / 4);
  cvt_bf16_kernel<<<1024, 256, 0, stream>>>(Wv, wqkv + 2097152,  1048576 / 4);
  cvt_bf16_kernel<<<1024, 256, 0, stream>>>(Wo, wob,             1048576 / 4);
  bias_cat_kernel<<<12, 256, 0, stream>>>(bq, bk, bv, bcat);
  gate_kernel<<<256, 256, 0, stream>>>(x, Wg, bg, gateb);

  // fused QKV projection: [4096,1024] @ [3072,1024]^T
  gemm_bt<1><<<dim3(24, 32), 256, 0, stream>>>(xb, wqkv, bcat, qkv, MTOT, 3072, 1024);

  // RoPE (q scaled by 0.125*log2e) + V transpose
  rope_kernel<<<8192, 256, 0, stream>>>(qkv, cosb, sinb, q_r, k_r);
  vtrans_kernel<<<dim3(32, 32), 256, 0, stream>>>(qkv, v_t);

  // windowed causal flash attention + gate (LDS-free, in-register softmax)
  attn_kernel<<<2048, 64, 0, stream>>>(q_r, k_r, v_t, gateb, attn);

  // output projection: [4096,1024] @ [1024,1024]^T + bo -> f32 out
  gemm_bt<0><<<dim3(8, 32), 256, 0, stream>>>(attn, wob, bo, out, MTOT, 1024, 1024);
}